// Round 1
// baseline (198.769 us; speedup 1.0000x reference)
//
#include <hip/hip_runtime.h>

// NoisyTopExpertsPerItemRouter: G=32,S=1024,H=2048,E=64,K=2 (top-2)
// N = G*S = 32768 rows.
// Outputs (concat, float32): idx (N*2) | w (N*2) | aux (1) | probs (N*64)

constexpr int GS  = 32768;
constexpr int EXP = 64;
constexpr int HID = 2048;
constexpr int BM  = 64;   // rows per block
constexpr int BK  = 32;   // K chunk

__global__ __launch_bounds__(256)
void router_kernel(const float* __restrict__ tokens,
                   const float* __restrict__ noise,
                   const float* __restrict__ W,
                   const float* __restrict__ bias,
                   float* __restrict__ out,
                   float* __restrict__ ws)
{
    __shared__ float As[BK][BM + 4];     // A^T tile: As[k][m]
    __shared__ float Bs[BK][EXP + 4];    // W^T tile: Bs[k][e]
    __shared__ float lg[BM][EXP + 1];    // logits (pre bias/noise)
    __shared__ float red[8][EXP];        // cross-wave: 4 imp + 4 cnt

    const int tid  = threadIdx.x;
    const int row0 = blockIdx.x * BM;

    // compute-thread mapping: 16x16 grid, 4x4 micro-tile
    const int tx = tid & 15;
    const int ty = tid >> 4;

    // load mapping: 32 rows x 8 threads x float4 per pass (2 passes)
    const int lr = tid >> 3;          // 0..31
    const int lc = (tid & 7) << 2;    // 0,4,...,28

    // f64 accumulators (chunked f32 inner sums keep ordering error ~4e-8,
    // needed so top-2 index ordering matches the high-precision reference)
    double acc[4][4];
    #pragma unroll
    for (int i = 0; i < 4; ++i)
        #pragma unroll
        for (int j = 0; j < 4; ++j) acc[i][j] = 0.0;

    const float* Ag = tokens + (size_t)row0 * HID;

    for (int kb = 0; kb < HID; kb += BK) {
        float4 a0 = *(const float4*)(Ag + (size_t)lr        * HID + kb + lc);
        float4 a1 = *(const float4*)(Ag + (size_t)(lr + 32) * HID + kb + lc);
        float4 b0 = *(const float4*)(W  + (size_t)lr        * HID + kb + lc);
        float4 b1 = *(const float4*)(W  + (size_t)(lr + 32) * HID + kb + lc);
        __syncthreads();   // previous chunk's compute done before overwrite
        As[lc + 0][lr]      = a0.x; As[lc + 1][lr]      = a0.y;
        As[lc + 2][lr]      = a0.z; As[lc + 3][lr]      = a0.w;
        As[lc + 0][lr + 32] = a1.x; As[lc + 1][lr + 32] = a1.y;
        As[lc + 2][lr + 32] = a1.z; As[lc + 3][lr + 32] = a1.w;
        Bs[lc + 0][lr]      = b0.x; Bs[lc + 1][lr]      = b0.y;
        Bs[lc + 2][lr]      = b0.z; Bs[lc + 3][lr]      = b0.w;
        Bs[lc + 0][lr + 32] = b1.x; Bs[lc + 1][lr + 32] = b1.y;
        Bs[lc + 2][lr + 32] = b1.z; Bs[lc + 3][lr + 32] = b1.w;
        __syncthreads();

        float c[4][4];
        #pragma unroll
        for (int i = 0; i < 4; ++i)
            #pragma unroll
            for (int j = 0; j < 4; ++j) c[i][j] = 0.f;

        #pragma unroll
        for (int k = 0; k < BK; ++k) {
            float4 av = *(const float4*)&As[k][ty << 2];
            float4 bv = *(const float4*)&Bs[k][tx << 2];
            float a_[4] = {av.x, av.y, av.z, av.w};
            float b_[4] = {bv.x, bv.y, bv.z, bv.w};
            #pragma unroll
            for (int i = 0; i < 4; ++i)
                #pragma unroll
                for (int j = 0; j < 4; ++j)
                    c[i][j] = fmaf(a_[i], b_[j], c[i][j]);
        }
        #pragma unroll
        for (int i = 0; i < 4; ++i)
            #pragma unroll
            for (int j = 0; j < 4; ++j) acc[i][j] += (double)c[i][j];
    }

    __syncthreads();
    #pragma unroll
    for (int i = 0; i < 4; ++i)
        #pragma unroll
        for (int j = 0; j < 4; ++j)
            lg[(ty << 2) + i][(tx << 2) + j] = (float)acc[i][j];
    __syncthreads();

    // ---- per-row epilogue: 4 waves x 16 rows ----
    const int wid  = tid >> 6;
    const int lane = tid & 63;

    float* out_idx   = out;
    float* out_w     = out + 2 * GS;
    float* out_probs = out + 4 * GS + 1;

    const float blane = bias[lane];
    float impL = 0.f, cntL = 0.f;

    for (int rr = 0; rr < 16; ++rr) {
        const int r = (wid << 4) + rr;
        const size_t row = (size_t)row0 + r;
        float v = lg[r][lane] + blane + noise[row * EXP + lane];

        float m = v;
        #pragma unroll
        for (int off = 32; off >= 1; off >>= 1)
            m = fmaxf(m, __shfl_xor(m, off));
        float e = expf(v - m);
        float s = e;
        #pragma unroll
        for (int off = 32; off >= 1; off >>= 1)
            s += __shfl_xor(s, off);
        float p = e / s;

        out_probs[row * EXP + lane] = p;
        impL += p;
        cntL += (p > 0.f) ? 1.f : 0.f;

        // top-1 (ties -> lower index, matches lax.top_k stability)
        float v1 = p; int i1 = lane;
        #pragma unroll
        for (int off = 32; off >= 1; off >>= 1) {
            float ov = __shfl_xor(v1, off);
            int   oi = __shfl_xor(i1, off);
            if (ov > v1 || (ov == v1 && oi < i1)) { v1 = ov; i1 = oi; }
        }
        // top-2: exclude winner lane
        float v2 = (lane == i1) ? -1.f : p; int i2 = lane;
        #pragma unroll
        for (int off = 32; off >= 1; off >>= 1) {
            float ov = __shfl_xor(v2, off);
            int   oi = __shfl_xor(i2, off);
            if (ov > v2 || (ov == v2 && oi < i2)) { v2 = ov; i2 = oi; }
        }
        if (lane == 0) {
            float denom = v1 + v2 + 1e-9f;
            out_idx[row * 2 + 0] = (float)i1;
            out_idx[row * 2 + 1] = (float)i2;
            out_w[row * 2 + 0] = v1 / denom;
            out_w[row * 2 + 1] = v2 / denom;
        }
    }

    red[wid][lane]     = impL;
    red[4 + wid][lane] = cntL;
    __syncthreads();
    if (tid < EXP) {
        float t1 = red[0][tid] + red[1][tid] + red[2][tid] + red[3][tid];
        float t2 = red[4][tid] + red[5][tid] + red[6][tid] + red[7][tid];
        atomicAdd(&ws[tid], t1);
        atomicAdd(&ws[EXP + tid], t2);
    }
}

__global__ void aux_kernel(const float* __restrict__ ws, float* __restrict__ out)
{
    const int lane = threadIdx.x;  // 64 threads
    float x = ws[lane] * ws[EXP + lane];   // importance * load
    float s = x;
    #pragma unroll
    for (int off = 32; off >= 1; off >>= 1)
        s += __shfl_xor(s, off);
    float mean = s * (1.f / 64.f);
    float d = x - mean;
    float ss = d * d;
    #pragma unroll
    for (int off = 32; off >= 1; off >>= 1)
        ss += __shfl_xor(ss, off);
    if (lane == 0)
        out[4 * GS] = 0.01f * (ss / 63.f);   // var ddof=1, * 0.01
}

extern "C" void kernel_launch(void* const* d_in, const int* in_sizes, int n_in,
                              void* d_out, int out_size, void* d_ws, size_t ws_size,
                              hipStream_t stream)
{
    const float* tokens = (const float*)d_in[0];
    const float* noise  = (const float*)d_in[1];
    const float* W      = (const float*)d_in[2];
    const float* bias   = (const float*)d_in[3];
    float* out = (float*)d_out;
    float* ws  = (float*)d_ws;

    // zero importance/load accumulators (ws not re-poisoned between replays,
    // so must reset every call)
    hipMemsetAsync(ws, 0, 2 * EXP * sizeof(float), stream);

    router_kernel<<<GS / BM, 256, 0, stream>>>(tokens, noise, W, bias, out, ws);
    aux_kernel<<<1, 64, 0, stream>>>(ws, out);
}